// Round 10
// baseline (719.064 us; speedup 1.0000x reference)
//
#include <hip/hip_runtime.h>
#include <math.h>

// Problem constants
#define B_ 2
#define S_ 2048
#define H_ 32
#define KV_ 8
#define D_ 128
#define T_ 4096
#define HID_ 4096
#define OQKV_ 6144

typedef __attribute__((ext_vector_type(4))) float f32x4;
typedef __attribute__((ext_vector_type(4))) int i32x4;
typedef __attribute__((ext_vector_type(8))) __bf16 bf16x8;
typedef __attribute__((ext_vector_type(8))) unsigned short u16x8;
typedef unsigned short u16;
typedef signed char s8;

// float -> bf16 bits, RTNE (finite inputs only)
__device__ __forceinline__ u16 f2b(float f) {
  unsigned x = __float_as_uint(f);
  return (u16)((x + 0x7FFFu + ((x >> 16) & 1u)) >> 16);
}
__device__ __forceinline__ float b2f(u16 u) {
  return __uint_as_float(((unsigned)u) << 16);
}

__device__ __forceinline__ void async16(const void* g, void* l) {
  __builtin_amdgcn_global_load_lds((__attribute__((address_space(1))) void*)g,
                                   (__attribute__((address_space(3))) void*)l,
                                   16, 0, 0);
}

__device__ __forceinline__ bf16x8 ld8(const u16* p) { return *(const bf16x8*)p; }

__device__ __forceinline__ f32x4 mfma16x16(bf16x8 a, bf16x8 b, f32x4 c) {
  return __builtin_amdgcn_mfma_f32_16x16x32_bf16(a, b, c, 0, 0, 0);
}

__device__ __forceinline__ bf16x8 ones8() {
  union { u16x8 u; bf16x8 b; } c;
  c.u = u16x8{0x3F80, 0x3F80, 0x3F80, 0x3F80, 0x3F80, 0x3F80, 0x3F80, 0x3F80};
  return c.b;
}

// raw barrier / counted waits (memory clobber = compiler fence, rule #18)
#define SBAR() asm volatile("s_barrier" ::: "memory")
#define WAITV(n) asm volatile("s_waitcnt vmcnt(" #n ")" ::: "memory")

// ---------------- int32 -> int8 pack (values already in int8 range) ----------------
__global__ __launch_bounds__(256) void pack_i8(const int* __restrict__ w,
                                               s8* __restrict__ out) {
  size_t base = ((size_t)blockIdx.x * 256 + threadIdx.x) * 4;
  int4 v = *(const int4*)(w + base);
  unsigned r = (unsigned)(v.x & 255) | ((unsigned)(v.y & 255) << 8) |
               ((unsigned)(v.z & 255) << 16) | ((unsigned)v.w << 24);
  *(unsigned*)(out + base) = r;
}

// NeoX RoPE in-place on bf16 qkv[t][6144]: q heads 0..31, k heads 32..39
__global__ __launch_bounds__(256) void rope_kernel(u16* __restrict__ qkv) {
  int idx = blockIdx.x * 256 + threadIdx.x;   // T * 40 * 64 total
  int t = idx / 2560;
  int r = idx - t * 2560;
  int head = r >> 6;
  int d = r & 63;
  int col = (head < 32) ? (head * 128 + d) : (4096 + (head - 32) * 128 + d);
  size_t base = (size_t)t * 6144 + col;
  float x1 = b2f(qkv[base]);
  float x2 = b2f(qkv[base + 64]);
  float e = (float)d * 0.015625f;                      // d/64 exact
  float freq = exp2f(e * -19.931568569324174f);        // 1e6^-e
  float ang = (float)(t & 2047) * freq;                // pos = t mod S
  float sn, cs;
  sincosf(ang, &sn, &cs);
  qkv[base] = f2b(x1 * cs - x2 * sn);
  qkv[base + 64] = f2b(x2 * cs + x1 * sn);
}

// V slice of qkv -> VT[b][kv][d][s] via LDS tile transpose. grid (32,2,16).
__global__ __launch_bounds__(256) void vt_transpose(const u16* __restrict__ qkv,
                                                    u16* __restrict__ vt) {
  __shared__ u16 tile[64][65];                 // +1 pad kills bank conflicts
  const int s0 = blockIdx.x * 64, d0 = blockIdx.y * 64;
  const int bk = blockIdx.z, b = bk >> 3, kv = bk & 7;
  const int tid = threadIdx.x;
  const int rr = tid >> 3, cc = tid & 7;
#pragma unroll
  for (int it = 0; it < 2; it++) {
    int r = it * 32 + rr;
    u16x8 v = *(const u16x8*)(qkv + (size_t)(b * 2048 + s0 + r) * 6144 + 5120 +
                              kv * 128 + d0 + cc * 8);
#pragma unroll
    for (int k = 0; k < 8; k++) tile[r][cc * 8 + k] = v[k];
  }
  __syncthreads();
#pragma unroll
  for (int it = 0; it < 2; it++) {
    int d = it * 32 + rr;
    u16x8 o;
#pragma unroll
    for (int k = 0; k < 8; k++) o[k] = tile[cc * 8 + k][d];
    *(u16x8*)(vt + (size_t)(bk * 128 + d0 + d) * 2048 + s0 + cc * 8) = o;
  }
}

// ---------------- int8 GEMM with per-128-group scales ----------------
// C[m,n] = rowscale[m] * sum_g sB[n,g] * sum_{k in g} A[m,k]*Bw[n,k]
// 128x64 tile, 4 waves each owning 32x64, __launch_bounds__(256,4).
// T3/T4 schedule: BK=64 double-buffer; raw s_barrier + COUNTED
// s_waitcnt vmcnt(3) so each tile's 3 per-wave async16s stay in flight
// across two barriers (depth-2 prefetch). No vmcnt(0) drains in steady
// state (R9's __syncthreads drained twice per group = the ~33% idle).
// Invariant entering group g: buf0 = tile 2g ready; buf1 = tile 2g+1 in
// flight (3/wave). Writes to a buffer happen only after the barrier that
// postdates all reads of it; vmcnt counts retire in issue order, so
// vmcnt(3) after staging t+2 proves t+1 complete, per wave; barrier makes
// it global. Tail groups use vmcnt(0) (uniform branch).
__device__ __forceinline__ void store_out(float* p, float v) { *p = v; }
__device__ __forceinline__ void store_out(u16* p, float v) { *p = f2b(v); }

template <typename OutT>
__global__ __launch_bounds__(256, 4) void gemm_i8(const s8* __restrict__ A,
                                                  const s8* __restrict__ Bw,
                                                  const float* __restrict__ sB,
                                                  const float* __restrict__ rowscale,
                                                  OutT* __restrict__ C,
                                                  int M, int N, int K) {
  __shared__ __align__(16) s8 As[2][128 * 64];
  __shared__ __align__(16) s8 Bs[2][64 * 64];
  __shared__ float Ss[64][33];                 // [local n][group], padded
  const int tid = threadIdx.x;
  const int lane = tid & 63;
  const int wv = tid >> 6;                     // 0..3; wave owns rows wv*32..+31
  const int m0 = blockIdx.y * 128, n0 = blockIdx.x * 64;
  const int g = lane >> 4, c15 = lane & 15;
  const int KG = K >> 7;                       // 32 groups (2 BK=64 steps each)
  const int NT = K >> 6;                       // 64 tiles

  // preload this block's scale panel (contiguous, coalesced)
  for (int i = tid; i < 64 * 32; i += 256)
    Ss[i >> 5][i & 31] = sB[(size_t)n0 * 32 + i];

  f32x4 acc[2][4] = {};

  // staging: 16-row x 64B chunks, rotation swizzle (verified R8 layout).
  const int srow = lane >> 2;                  // 0..15 row within chunk
  const int pch = lane & 3;                    // physical 16B chunk slot
  const int scol = (((pch - (srow >> 1)) & 3)) * 16;  // logical chunk -> col
  const s8* Ag0 = A + (size_t)(m0 + (2 * wv) * 16 + srow) * K + scol;
  const s8* Ag1 = A + (size_t)(m0 + (2 * wv + 1) * 16 + srow) * K + scol;
  const s8* Bg = Bw + (size_t)(n0 + wv * 16 + srow) * K + scol;
  const int la0 = (2 * wv) * 1024 + lane * 16;
  const int la1 = (2 * wv + 1) * 1024 + lane * 16;
  const int lb = wv * 1024 + lane * 16;

  const int aoff = (wv * 32 + c15) * 64 + ((g + (c15 >> 1)) & 3) * 16;
  const int boff = c15 * 64 + ((g + (c15 >> 1)) & 3) * 16;

  // prologue: tile 0 -> buf0, tile 1 -> buf1; wait tile0 + Ss writes
  async16(Ag0, &As[0][0] + la0);
  async16(Ag1, &As[0][0] + la1);
  async16(Bg, &Bs[0][0] + lb);
  async16(Ag0 + 64, &As[1][0] + la0);
  async16(Ag1 + 64, &As[1][0] + la1);
  async16(Bg + 64, &Bs[1][0] + lb);
  asm volatile("s_waitcnt vmcnt(3) lgkmcnt(0)" ::: "memory");
  SBAR();

  for (int grp = 0; grp < KG; ++grp) {
    i32x4 iacc[2][4];
    // ---- step even: tile 2g from buf0 (init) ----
    {
      i32x4 af[2], bf[4];
#pragma unroll
      for (int i = 0; i < 2; i++)
        af[i] = *(const i32x4*)(&As[0][0] + aoff + i * 1024);
#pragma unroll
      for (int j = 0; j < 4; j++)
        bf[j] = *(const i32x4*)(&Bs[0][0] + boff + j * 1024);
#pragma unroll
      for (int i = 0; i < 2; i++)
#pragma unroll
        for (int j = 0; j < 4; j++)
          iacc[i][j] = __builtin_amdgcn_mfma_i32_16x16x64_i8(
              af[i], bf[j], (i32x4){0, 0, 0, 0}, 0, 0, 0);
    }
    SBAR();                                    // all waves done reading buf0
    {
      const int t2 = 2 * grp + 2;
      if (t2 < NT) {                           // stage tile 2g+2 -> buf0
        const int kb = t2 << 6;
        async16(Ag0 + kb, &As[0][0] + la0);
        async16(Ag1 + kb, &As[0][0] + la1);
        async16(Bg + kb, &Bs[0][0] + lb);
        WAITV(3);                              // tile 2g+1 complete
      } else {
        WAITV(0);
      }
    }
    SBAR();                                    // buf1 (tile 2g+1) ready
    // ---- step odd: tile 2g+1 from buf1 (accumulate) ----
    {
      i32x4 af[2], bf[4];
#pragma unroll
      for (int i = 0; i < 2; i++)
        af[i] = *(const i32x4*)(&As[1][0] + aoff + i * 1024);
#pragma unroll
      for (int j = 0; j < 4; j++)
        bf[j] = *(const i32x4*)(&Bs[1][0] + boff + j * 1024);
#pragma unroll
      for (int i = 0; i < 2; i++)
#pragma unroll
        for (int j = 0; j < 4; j++)
          iacc[i][j] = __builtin_amdgcn_mfma_i32_16x16x64_i8(
              af[i], bf[j], iacc[i][j], 0, 0, 0);
    }
    SBAR();                                    // all waves done reading buf1
    {
      const int t3 = 2 * grp + 3;
      if (t3 < NT) {                           // stage tile 2g+3 -> buf1
        const int kb = t3 << 6;
        async16(Ag0 + kb, &As[1][0] + la0);
        async16(Ag1 + kb, &As[1][0] + la1);
        async16(Bg + kb, &Bs[1][0] + lb);
      }
    }
    // per-group rescale overlaps the in-flight prefetch
#pragma unroll
    for (int j = 0; j < 4; j++) {
      const float sc = Ss[j * 16 + c15][grp];
#pragma unroll
      for (int i = 0; i < 2; i++)
#pragma unroll
        for (int r = 0; r < 4; r++)
          acc[i][j][r] += sc * (float)iacc[i][j][r];
    }
    if (2 * grp + 3 < NT) { WAITV(3); } else { WAITV(0); }
    SBAR();                                    // buf0 (tile 2g+2) ready
  }

#pragma unroll
  for (int i = 0; i < 2; i++) {
#pragma unroll
    for (int r = 0; r < 4; r++) {
      int m = m0 + wv * 32 + i * 16 + g * 4 + r;
      float scm = rowscale[m];
#pragma unroll
      for (int j = 0; j < 4; j++) {
        int n = n0 + j * 16 + c15;
        store_out(C + (size_t)m * N + n, acc[i][j][r] * scm);
      }
    }
  }
}

// ---------------- flash attention (causal, GQA 4:1), block-lockstep LDS-staged ----------------
struct AttnState {
  f32x4 acc[2][9];
  float mrun[2][4];
};

template <bool FULL>
__device__ __forceinline__ void qk_phase(int j0, int q0w, const u16* Ksp,
                                         const bf16x8 qf[2][4],
                                         f32x4 (&sc)[2][4], int g, int c15) {
  const int qmax = q0w + 31;
#pragma unroll
  for (int nt = 0; nt < 4; nt++) {
    if (FULL || (j0 + nt * 16 <= qmax)) {
      bf16x8 kf[4];
#pragma unroll
      for (int c = 0; c < 4; c++)
        kf[c] = ld8(Ksp + (nt * 16 + c15) * 128 +
                    (((g + 4 * c) ^ (c15 & 7)) * 8));
      f32x4 s0 = {0.f, 0.f, 0.f, 0.f}, s1 = {0.f, 0.f, 0.f, 0.f};
#pragma unroll
      for (int c = 0; c < 4; c++) {
        s0 = mfma16x16(qf[0][c], kf[c], s0);
        s1 = mfma16x16(qf[1][c], kf[c], s1);
      }
      if (FULL) {
#pragma unroll
        for (int r = 0; r < 4; r++) {
          sc[0][nt][r] = s0[r] * 0.08838834764831845f;
          sc[1][nt][r] = s1[r] * 0.08838834764831845f;
        }
      } else {
        const int key = j0 + nt * 16 + c15;
#pragma unroll
        for (int r = 0; r < 4; r++) {
          sc[0][nt][r] =
              (key <= q0w + g * 4 + r) ? s0[r] * 0.08838834764831845f : -INFINITY;
          sc[1][nt][r] =
              (key <= q0w + 16 + g * 4 + r) ? s1[r] * 0.08838834764831845f : -INFINITY;
        }
      }
    }
  }
}

template <bool FULL>
__device__ __forceinline__ void smax_pv(int j0, int q0w, const u16* Vsp,
                                        u16* pw0, u16* pw1, f32x4 (&sc)[2][4],
                                        AttnState& st, int g, int c15,
                                        const bf16x8 vones) {
  const int qmax = q0w + 31;
#pragma unroll
  for (int m = 0; m < 2; m++) {
    u16* pw = m ? pw1 : pw0;
    float alpha[4];
#pragma unroll
    for (int r = 0; r < 4; r++) {
      float rm = -INFINITY;
#pragma unroll
      for (int nt = 0; nt < 4; nt++)
        if (FULL || (j0 + nt * 16 <= qmax)) rm = fmaxf(rm, sc[m][nt][r]);
      rm = fmaxf(rm, __shfl_xor(rm, 1));
      rm = fmaxf(rm, __shfl_xor(rm, 2));
      rm = fmaxf(rm, __shfl_xor(rm, 4));
      rm = fmaxf(rm, __shfl_xor(rm, 8));
      float mnew = fmaxf(st.mrun[m][r], rm);
      alpha[r] = __expf(st.mrun[m][r] - mnew);
      st.mrun[m][r] = mnew;
#pragma unroll
      for (int nt = 0; nt < 4; nt++) {
        float pv = (FULL || (j0 + nt * 16 <= qmax))
                       ? __expf(sc[m][nt][r] - mnew) : 0.0f;
        pw[(g * 4 + r) * 72 + nt * 16 + c15] = f2b(pv);
      }
    }
#pragma unroll
    for (int dt = 0; dt < 9; dt++)
#pragma unroll
      for (int r = 0; r < 4; r++) st.acc[m][dt][r] *= alpha[r];
  }
  // PV: P via per-wave LDS round-trip; V fragments from the staged LDS tile
#pragma unroll
  for (int kc = 0; kc < 2; kc++) {
    bf16x8 pf0 = ld8(pw0 + c15 * 72 + kc * 32 + g * 8);
    bf16x8 pf1 = ld8(pw1 + c15 * 72 + kc * 32 + g * 8);
#pragma unroll
    for (int dt = 0; dt < 8; dt++) {
      bf16x8 vf = ld8(Vsp + (dt * 16 + c15) * 64 +
                      (((g + 4 * kc) ^ (c15 & 7)) * 8));
      st.acc[0][dt] = mfma16x16(pf0, vf, st.acc[0][dt]);
      st.acc[1][dt] = mfma16x16(pf1, vf, st.acc[1][dt]);
    }
    st.acc[0][8] = mfma16x16(pf0, vones, st.acc[0][8]);
    st.acc[1][8] = mfma16x16(pf1, vones, st.acc[1][8]);
  }
}

// grid (32 h, 2 b, 16 qb-desc), block 256.
__global__ __launch_bounds__(256, 2) void attn_kernel(const u16* __restrict__ qkvb,
                                                      const u16* __restrict__ vtb,
                                                      float* __restrict__ out) {
  __shared__ __align__(16) u16 Ks[64 * 128];        // [key][d], chunk-swizzled
  __shared__ __align__(16) u16 Vs[2][128 * 64];     // [d][key], chunk-swizzled
  __shared__ __align__(16) u16 Ps[4][2][16 * 72];   // per-wave, per-m-tile P
  const int tid = threadIdx.x, lane = tid & 63, wv = tid >> 6;
  const int g = lane >> 4, c15 = lane & 15;
  const int h = blockIdx.x, b = blockIdx.y, qb = 15 - (int)blockIdx.z;
  const int kvh = h >> 2;
  const int Q0 = qb * 128;
  const int q0w = Q0 + wv * 32;                     // this wave's q-tile base
  const int nsteps = 2 * qb + 2;
  const bf16x8 vones = ones8();
  u16* pw0 = &Ps[wv][0][0];
  u16* pw1 = &Ps[wv][1][0];

  // staging lane decomposition (async16: LDS = uniform base + lane*16B)
  const int keyl = lane >> 4, kch = lane & 15;      // K: 4 rows x 16 chunks
  const int dll = lane >> 3, vch = lane & 7;        // V: 8 rows x 8 chunks
  const u16* Kg = qkvb + (size_t)(b * 2048) * 6144 + 4096 + kvh * 128;
  const u16* Vg = vtb + (size_t)((b * 8 + kvh) * 128) * 2048;

  auto stageK = [&](int j0) {
#pragma unroll
    for (int i = 0; i < 4; i++) {
      const int key = wv * 16 + i * 4 + keyl;
      async16(Kg + (size_t)(j0 + key) * 6144 + ((kch ^ (key & 7)) * 8),
              (u16*)Ks + (wv * 16 + i * 4) * 128 + lane * 8);
    }
  };
  auto stageV = [&](int j0, int vb) {
#pragma unroll
    for (int i = 0; i < 4; i++) {
      const int d = wv * 32 + i * 8 + dll;
      async16(Vg + (size_t)d * 2048 + j0 + ((vch ^ (d & 7)) * 8),
              (u16*)&Vs[vb][0] + (wv * 32 + i * 8) * 64 + lane * 8);
    }
  };

  // Q fragments (global, once per block)
  bf16x8 qf[2][4];
#pragma unroll
  for (int m = 0; m < 2; m++) {
    const u16* qp =
        qkvb + (size_t)(b * 2048 + q0w + m * 16 + c15) * 6144 + h * 128 + g * 8;
#pragma unroll
    for (int c = 0; c < 4; c++) qf[m][c] = ld8(qp + c * 32);
  }

  AttnState st;
#pragma unroll
  for (int m = 0; m < 2; m++) {
#pragma unroll
    for (int dt = 0; dt < 9; dt++) st.acc[m][dt] = f32x4{0.f, 0.f, 0.f, 0.f};
#pragma unroll
    for (int r = 0; r < 4; r++) st.mrun[m][r] = -INFINITY;
  }

  stageK(0);
  stageV(0, 0);

  for (int jt = 0; jt < nsteps; ++jt) {
    const int j0 = jt * 64;
    __syncthreads();   // B1: this step's K/V staged; prior buffer reads done
    // per-wave causal mode: 0=FULL, 1=MASK, 2=SKIP
    const int mode = (j0 + 64 <= q0w) ? 0 : ((j0 <= q0w + 31) ? 1 : 2);
    f32x4 sc[2][4];
    if (mode == 0) qk_phase<true>(j0, q0w, (const u16*)Ks, qf, sc, g, c15);
    else if (mode == 1) qk_phase<false>(j0, q0w, (const u16*)Ks, qf, sc, g, c15);
    __syncthreads();   // B2: all waves' Ks reads complete
    if (jt + 1 < nsteps) {                 // stage next tiles; softmax+PV
      stageK(j0 + 64);                     // hides their latency
      stageV(j0 + 64, (jt + 1) & 1);
    }
    const u16* Vsp = (const u16*)&Vs[jt & 1][0];
    if (mode == 0) smax_pv<true>(j0, q0w, Vsp, pw0, pw1, sc, st, g, c15, vones);
    else if (mode == 1) smax_pv<false>(j0, q0w, Vsp, pw0, pw1, sc, st, g, c15, vones);
  }

  // epilogue: normalize by l (= acc[8]) and store fp32
#pragma unroll
  for (int m = 0; m < 2; m++)
#pragma unroll
    for (int r = 0; r < 4; r++) {
      const int row = q0w + m * 16 + g * 4 + r;
      float inv = 1.0f / st.acc[m][8][r];
      float* op = out + (size_t)(b * 2048 + row) * 4096 + h * 128;
#pragma unroll
      for (int dt = 0; dt < 8; dt++) op[dt * 16 + c15] = st.acc[m][dt][r] * inv;
    }
}

// ---------------- per-row quantization (fp32 attn -> int8 + scale) ----------------
__global__ __launch_bounds__(256) void quant_kernel(const float* __restrict__ attn,
                                                    s8* __restrict__ aq,
                                                    float* __restrict__ ascale) {
  const int t = blockIdx.x, tid = threadIdx.x;
  const float* row = attn + (size_t)t * 4096;
  f32x4 v[4];
  float am = 0.f;
#pragma unroll
  for (int i = 0; i < 4; i++) {
    v[i] = *(const f32x4*)(row + tid * 16 + i * 4);
#pragma unroll
    for (int r = 0; r < 4; r++) am = fmaxf(am, fabsf(v[i][r]));
  }
#pragma unroll
  for (int m = 1; m <= 32; m <<= 1) am = fmaxf(am, __shfl_xor(am, m));
  __shared__ float red[4];
  if ((tid & 63) == 0) red[tid >> 6] = am;
  __syncthreads();
  am = fmaxf(fmaxf(red[0], red[1]), fmaxf(red[2], red[3]));
  float asc = fmaxf(am, 1e-6f) / 127.0f;
  if (tid == 0) ascale[t] = asc;
  int w[4];
#pragma unroll
  for (int i = 0; i < 4; i++) {
    int bytes[4];
#pragma unroll
    for (int r = 0; r < 4; r++) {
      float q = rintf(v[i][r] / asc);
      q = fminf(127.0f, fmaxf(-127.0f, q));
      bytes[r] = ((int)q) & 255;
    }
    w[i] = bytes[0] | (bytes[1] << 8) | (bytes[2] << 16) | (bytes[3] << 24);
  }
  *(int4*)(aq + (size_t)t * 4096 + tid * 16) = int4{w[0], w[1], w[2], w[3]};
}

// ---------------- launch ----------------
extern "C" void kernel_launch(void* const* d_in, const int* in_sizes, int n_in,
                              void* d_out, int out_size, void* d_ws, size_t ws_size,
                              hipStream_t stream) {
  const int* q_hidden = (const int*)d_in[0];
  const float* q_scale = (const float*)d_in[1];
  const int* w_qkv = (const int*)d_in[3];
  const float* s_qkv = (const float*)d_in[4];
  const int* w_o = (const int*)d_in[5];
  const float* s_o = (const float*)d_in[6];
  float* out = (float*)d_out;

  char* ws = (char*)d_ws;
  const size_t MB = 1024 * 1024;
  // ws layout (96 MB peak, regions reused across phases):
  s8* WB = (s8*)(ws);                  // [0,24MB) w_qkv i8 (dead after gemm1)
  u16* QKVB = (u16*)(ws + 48 * MB);    // [48,96MB) qkv bf16 (dead after attention)
  u16* VTB = (u16*)(ws);               // [0,8MB) V^T (after gemm1)
  s8* ATTNQ = (s8*)(ws + 8 * MB);      // [8,~24.8MB) attn_q i8
  float* ASC = (float*)(ws + 25 * MB); // [25MB,+16KB) per-row scales
  s8* WOB = (s8*)(ws + 48 * MB);       // [48,~64.8MB) w_o i8 (after attention)
  s8* XB = (s8*)d_out;                 // x i8 in d_out (dead after gemm1)

  pack_i8<<<16384, 256, 0, stream>>>(q_hidden, XB);
  pack_i8<<<24576, 256, 0, stream>>>(w_qkv, WB);
  gemm_i8<u16><<<dim3(96, 32), 256, 0, stream>>>(XB, WB, s_qkv, q_scale, QKVB,
                                                 T_, OQKV_, HID_);
  rope_kernel<<<40960, 256, 0, stream>>>(QKVB);
  vt_transpose<<<dim3(32, 2, 16), 256, 0, stream>>>(QKVB, VTB);
  attn_kernel<<<dim3(32, 2, 16), 256, 0, stream>>>(QKVB, VTB, out);
  quant_kernel<<<4096, 256, 0, stream>>>(out, ATTNQ, ASC);
  pack_i8<<<16384, 256, 0, stream>>>(w_o, WOB);
  gemm_i8<float><<<dim3(64, 32), 256, 0, stream>>>(ATTNQ, WOB, s_o, ASC, out,
                                                   T_, HID_, HID_);
}

// Round 11
// 663.675 us; speedup vs baseline: 1.0835x; 1.0835x over previous
//
#include <hip/hip_runtime.h>
#include <math.h>

// Problem constants
#define B_ 2
#define S_ 2048
#define H_ 32
#define KV_ 8
#define D_ 128
#define T_ 4096
#define HID_ 4096
#define OQKV_ 6144

typedef __attribute__((ext_vector_type(4))) float f32x4;
typedef __attribute__((ext_vector_type(4))) int i32x4;
typedef __attribute__((ext_vector_type(8))) __bf16 bf16x8;
typedef __attribute__((ext_vector_type(4))) unsigned short u16x4;
typedef __attribute__((ext_vector_type(8))) unsigned short u16x8;
typedef unsigned short u16;
typedef signed char s8;

// float -> bf16 bits, RTNE (finite inputs only)
__device__ __forceinline__ u16 f2b(float f) {
  unsigned x = __float_as_uint(f);
  return (u16)((x + 0x7FFFu + ((x >> 16) & 1u)) >> 16);
}
__device__ __forceinline__ float b2f(u16 u) {
  return __uint_as_float(((unsigned)u) << 16);
}

__device__ __forceinline__ void async16(const void* g, void* l) {
  __builtin_amdgcn_global_load_lds((__attribute__((address_space(1))) void*)g,
                                   (__attribute__((address_space(3))) void*)l,
                                   16, 0, 0);
}

__device__ __forceinline__ bf16x8 ld8(const u16* p) { return *(const bf16x8*)p; }

__device__ __forceinline__ f32x4 mfma16x16(bf16x8 a, bf16x8 b, f32x4 c) {
  return __builtin_amdgcn_mfma_f32_16x16x32_bf16(a, b, c, 0, 0, 0);
}

__device__ __forceinline__ bf16x8 ones8() {
  union { u16x8 u; bf16x8 b; } c;
  c.u = u16x8{0x3F80, 0x3F80, 0x3F80, 0x3F80, 0x3F80, 0x3F80, 0x3F80, 0x3F80};
  return c.b;
}

// ---------------- int32 -> int8 pack (values already in int8 range) ----------------
__global__ __launch_bounds__(256) void pack_i8(const int* __restrict__ w,
                                               s8* __restrict__ out) {
  size_t base = ((size_t)blockIdx.x * 256 + threadIdx.x) * 4;
  int4 v = *(const int4*)(w + base);
  unsigned r = (unsigned)(v.x & 255) | ((unsigned)(v.y & 255) << 8) |
               ((unsigned)(v.z & 255) << 16) | ((unsigned)v.w << 24);
  *(unsigned*)(out + base) = r;
}

// NeoX RoPE in-place on bf16 qkv[t][6144]: q heads 0..31, k heads 32..39.
// 4 consecutive d per thread (u16x4 8B vector loads), __sincosf fast path
// (abs err ~1e-4 << bf16 eps 0.008). grid 10240 x 256 = T*40*16 threads.
__global__ __launch_bounds__(256) void rope_kernel(u16* __restrict__ qkv) {
  int idx = blockIdx.x * 256 + threadIdx.x;   // T * 40 * 16 total
  int t = idx / 640;
  int r = idx - t * 640;
  int head = r >> 4;
  int d0 = (r & 15) << 2;
  int col = (head < 32) ? (head * 128 + d0) : (4096 + (head - 32) * 128 + d0);
  size_t base = (size_t)t * 6144 + col;
  u16x4 a = *(const u16x4*)(qkv + base);
  u16x4 b = *(const u16x4*)(qkv + base + 64);
  float pos = (float)(t & 2047);               // pos = t mod S
  u16x4 o1, o2;
#pragma unroll
  for (int j = 0; j < 4; j++) {
    float e = (float)(d0 + j) * 0.015625f;     // d/64 exact
    float freq = exp2f(e * -19.931568569324174f);  // 1e6^-e
    float ang = pos * freq;
    float sn, cs;
    __sincosf(ang, &sn, &cs);
    float x1 = b2f(a[j]), x2 = b2f(b[j]);
    o1[j] = f2b(x1 * cs - x2 * sn);
    o2[j] = f2b(x2 * cs + x1 * sn);
  }
  *(u16x4*)(qkv + base) = o1;
  *(u16x4*)(qkv + base + 64) = o2;
}

// V slice of qkv -> VT[b][kv][d][s] via LDS tile transpose. grid (32,2,16).
__global__ __launch_bounds__(256) void vt_transpose(const u16* __restrict__ qkv,
                                                    u16* __restrict__ vt) {
  __shared__ u16 tile[64][65];                 // +1 pad kills bank conflicts
  const int s0 = blockIdx.x * 64, d0 = blockIdx.y * 64;
  const int bk = blockIdx.z, b = bk >> 3, kv = bk & 7;
  const int tid = threadIdx.x;
  const int rr = tid >> 3, cc = tid & 7;
#pragma unroll
  for (int it = 0; it < 2; it++) {
    int r = it * 32 + rr;
    u16x8 v = *(const u16x8*)(qkv + (size_t)(b * 2048 + s0 + r) * 6144 + 5120 +
                              kv * 128 + d0 + cc * 8);
#pragma unroll
    for (int k = 0; k < 8; k++) tile[r][cc * 8 + k] = v[k];
  }
  __syncthreads();
#pragma unroll
  for (int it = 0; it < 2; it++) {
    int d = it * 32 + rr;
    u16x8 o;
#pragma unroll
    for (int k = 0; k < 8; k++) o[k] = tile[cc * 8 + k][d];
    *(u16x8*)(vt + (size_t)(bk * 128 + d0 + d) * 2048 + s0 + cc * 8) = o;
  }
}

// ---------------- int8 GEMM with per-128-group scales (R9-verified) ----------------
// C[m,n] = rowscale[m] * sum_g sB[n,g] * sum_{k in g} A[m,k]*Bw[n,k]
// 128x64 block tile, 4 waves each owning 32x64. __launch_bounds__(256,4).
// BK=128 per step, statically-indexed halves; stage -> barrier -> compute.
// NOTE: do not re-touch the sync structure. R6 (runtime dbuf) tripled VALU;
// R7 (static dbuf, 1 drain) and R10 (counted vmcnt, 4 barriers) both lost
// to this 2-barrier shape. This is the structure's local optimum (164us).
__device__ __forceinline__ void store_out(float* p, float v) { *p = v; }
__device__ __forceinline__ void store_out(u16* p, float v) { *p = f2b(v); }

template <typename OutT>
__global__ __launch_bounds__(256, 4) void gemm_i8(const s8* __restrict__ A,
                                                  const s8* __restrict__ Bw,
                                                  const float* __restrict__ sB,
                                                  const float* __restrict__ rowscale,
                                                  OutT* __restrict__ C,
                                                  int M, int N, int K) {
  __shared__ __align__(16) s8 As[128 * 128];   // two 64-K halves of 128 rows
  __shared__ __align__(16) s8 Bs[64 * 128];    // two 64-K halves of 64 rows
  __shared__ float Ss[64][33];                 // [local n][group], padded
  const int tid = threadIdx.x;
  const int lane = tid & 63;
  const int wv = tid >> 6;                     // 0..3; wave owns rows wv*32..+31
  const int m0 = blockIdx.y * 128, n0 = blockIdx.x * 64;
  const int g = lane >> 4, c15 = lane & 15;
  const int KG = K >> 7;                       // 32 groups for K=4096

  // preload this block's scale panel (contiguous, coalesced)
  for (int i = tid; i < 64 * 32; i += 256)
    Ss[i >> 5][i & 31] = sB[(size_t)n0 * 32 + i];

  f32x4 acc[2][4] = {};

  // staging: 16-row x 64B chunks. A halves: 8 chunks (wave stages 2);
  // B halves: 4 chunks (wave stages 1). Same rotation swizzle as verified.
  const int srow = lane >> 2;                  // 0..15 row within chunk
  const int pch = lane & 3;                    // physical 16B chunk slot
  const int scol = (((pch - (srow >> 1)) & 3)) * 16;  // logical chunk -> col
  const s8* Ag0 = A + (size_t)(m0 + (2 * wv) * 16 + srow) * K + scol;
  const s8* Ag1 = A + (size_t)(m0 + (2 * wv + 1) * 16 + srow) * K + scol;
  const s8* Bg = Bw + (size_t)(n0 + wv * 16 + srow) * K + scol;
  s8* Al0 = As + (2 * wv) * 1024 + lane * 16;      // + sub*8192
  s8* Al1 = As + (2 * wv + 1) * 1024 + lane * 16;
  s8* Bl = Bs + wv * 1024 + lane * 16;             // + sub*4096

  const int aoff = (wv * 32 + c15) * 64 + ((g + (c15 >> 1)) & 3) * 16;
  const int boff = c15 * 64 + ((g + (c15 >> 1)) & 3) * 16;

  for (int grp = 0; grp < KG; ++grp) {
    const int kb = grp << 7;
    __syncthreads();                 // all waves' reads of prev step done
    async16(Ag0 + kb, Al0);          // sub0 (k 0..63 of group)
    async16(Ag1 + kb, Al1);
    async16(Bg + kb, Bl);
    async16(Ag0 + kb + 64, Al0 + 8192);  // sub1 (k 64..127)
    async16(Ag1 + kb + 64, Al1 + 8192);
    async16(Bg + kb + 64, Bl + 4096);
    __syncthreads();                 // vmcnt drain: whole 128-K tile staged

    i32x4 iacc[2][4];
#pragma unroll
    for (int sub = 0; sub < 2; sub++) {        // static: init vs accum
      i32x4 af[2], bf[4];
#pragma unroll
      for (int i = 0; i < 2; i++)
        af[i] = *(const i32x4*)(As + sub * 8192 + aoff + i * 1024);
#pragma unroll
      for (int j = 0; j < 4; j++)
        bf[j] = *(const i32x4*)(Bs + sub * 4096 + boff + j * 1024);
#pragma unroll
      for (int i = 0; i < 2; i++)
#pragma unroll
        for (int j = 0; j < 4; j++)
          iacc[i][j] = __builtin_amdgcn_mfma_i32_16x16x64_i8(
              af[i], bf[j], sub ? iacc[i][j] : (i32x4){0, 0, 0, 0}, 0, 0, 0);
    }
    // per-group rescale into fp32 master accumulator
#pragma unroll
    for (int j = 0; j < 4; j++) {
      const float sc = Ss[j * 16 + c15][grp];
#pragma unroll
      for (int i = 0; i < 2; i++)
#pragma unroll
        for (int r = 0; r < 4; r++)
          acc[i][j][r] += sc * (float)iacc[i][j][r];
    }
  }

#pragma unroll
  for (int i = 0; i < 2; i++) {
#pragma unroll
    for (int r = 0; r < 4; r++) {
      int m = m0 + wv * 32 + i * 16 + g * 4 + r;
      float scm = rowscale[m];
#pragma unroll
      for (int j = 0; j < 4; j++) {
        int n = n0 + j * 16 + c15;
        store_out(C + (size_t)m * N + n, acc[i][j][r] * scm);
      }
    }
  }
}

// ---------------- flash attention (causal, GQA 4:1), block-lockstep LDS-staged ----------------
// Block = 128 q-rows (4 waves x 32). K/V 64-key tiles staged once per block
// into LDS (async16, source-side XOR chunk swizzle -> conflict-free
// ds_read_b128 fragments), shared by all 4 waves: cache traffic / 4.
// T5: s_setprio(1) around MFMA clusters — blocks at different causal step
// counts give the CU scheduler phase-diverse waves to arbitrate.

struct AttnState {
  f32x4 acc[2][9];
  float mrun[2][4];
};

template <bool FULL>
__device__ __forceinline__ void qk_phase(int j0, int q0w, const u16* Ksp,
                                         const bf16x8 qf[2][4],
                                         f32x4 (&sc)[2][4], int g, int c15) {
  const int qmax = q0w + 31;
#pragma unroll
  for (int nt = 0; nt < 4; nt++) {
    if (FULL || (j0 + nt * 16 <= qmax)) {
      bf16x8 kf[4];
#pragma unroll
      for (int c = 0; c < 4; c++)
        kf[c] = ld8(Ksp + (nt * 16 + c15) * 128 +
                    (((g + 4 * c) ^ (c15 & 7)) * 8));
      f32x4 s0 = {0.f, 0.f, 0.f, 0.f}, s1 = {0.f, 0.f, 0.f, 0.f};
      __builtin_amdgcn_s_setprio(1);
#pragma unroll
      for (int c = 0; c < 4; c++) {
        s0 = mfma16x16(qf[0][c], kf[c], s0);
        s1 = mfma16x16(qf[1][c], kf[c], s1);
      }
      __builtin_amdgcn_s_setprio(0);
      if (FULL) {
#pragma unroll
        for (int r = 0; r < 4; r++) {
          sc[0][nt][r] = s0[r] * 0.08838834764831845f;
          sc[1][nt][r] = s1[r] * 0.08838834764831845f;
        }
      } else {
        const int key = j0 + nt * 16 + c15;
#pragma unroll
        for (int r = 0; r < 4; r++) {
          sc[0][nt][r] =
              (key <= q0w + g * 4 + r) ? s0[r] * 0.08838834764831845f : -INFINITY;
          sc[1][nt][r] =
              (key <= q0w + 16 + g * 4 + r) ? s1[r] * 0.08838834764831845f : -INFINITY;
        }
      }
    }
  }
}

template <bool FULL>
__device__ __forceinline__ void smax_pv(int j0, int q0w, const u16* Vsp,
                                        u16* pw0, u16* pw1, f32x4 (&sc)[2][4],
                                        AttnState& st, int g, int c15,
                                        const bf16x8 vones) {
  const int qmax = q0w + 31;
#pragma unroll
  for (int m = 0; m < 2; m++) {
    u16* pw = m ? pw1 : pw0;
    float alpha[4];
#pragma unroll
    for (int r = 0; r < 4; r++) {
      float rm = -INFINITY;
#pragma unroll
      for (int nt = 0; nt < 4; nt++)
        if (FULL || (j0 + nt * 16 <= qmax)) rm = fmaxf(rm, sc[m][nt][r]);
      rm = fmaxf(rm, __shfl_xor(rm, 1));
      rm = fmaxf(rm, __shfl_xor(rm, 2));
      rm = fmaxf(rm, __shfl_xor(rm, 4));
      rm = fmaxf(rm, __shfl_xor(rm, 8));
      float mnew = fmaxf(st.mrun[m][r], rm);
      alpha[r] = __expf(st.mrun[m][r] - mnew);
      st.mrun[m][r] = mnew;
#pragma unroll
      for (int nt = 0; nt < 4; nt++) {
        float pv = (FULL || (j0 + nt * 16 <= qmax))
                       ? __expf(sc[m][nt][r] - mnew) : 0.0f;
        pw[(g * 4 + r) * 72 + nt * 16 + c15] = f2b(pv);
      }
    }
#pragma unroll
    for (int dt = 0; dt < 9; dt++)
#pragma unroll
      for (int r = 0; r < 4; r++) st.acc[m][dt][r] *= alpha[r];
  }
  // PV: P via per-wave LDS round-trip; V fragments from the staged LDS tile
#pragma unroll
  for (int kc = 0; kc < 2; kc++) {
    bf16x8 pf0 = ld8(pw0 + c15 * 72 + kc * 32 + g * 8);
    bf16x8 pf1 = ld8(pw1 + c15 * 72 + kc * 32 + g * 8);
    __builtin_amdgcn_s_setprio(1);
#pragma unroll
    for (int dt = 0; dt < 8; dt++) {
      bf16x8 vf = ld8(Vsp + (dt * 16 + c15) * 64 +
                      (((g + 4 * kc) ^ (c15 & 7)) * 8));
      st.acc[0][dt] = mfma16x16(pf0, vf, st.acc[0][dt]);
      st.acc[1][dt] = mfma16x16(pf1, vf, st.acc[1][dt]);
    }
    st.acc[0][8] = mfma16x16(pf0, vones, st.acc[0][8]);
    st.acc[1][8] = mfma16x16(pf1, vones, st.acc[1][8]);
    __builtin_amdgcn_s_setprio(0);
  }
}

// grid (32 h, 2 b, 16 qb-desc), block 256.
__global__ __launch_bounds__(256, 2) void attn_kernel(const u16* __restrict__ qkvb,
                                                      const u16* __restrict__ vtb,
                                                      float* __restrict__ out) {
  __shared__ __align__(16) u16 Ks[64 * 128];        // [key][d], chunk-swizzled
  __shared__ __align__(16) u16 Vs[2][128 * 64];     // [d][key], chunk-swizzled
  __shared__ __align__(16) u16 Ps[4][2][16 * 72];   // per-wave, per-m-tile P
  const int tid = threadIdx.x, lane = tid & 63, wv = tid >> 6;
  const int g = lane >> 4, c15 = lane & 15;
  const int h = blockIdx.x, b = blockIdx.y, qb = 15 - (int)blockIdx.z;
  const int kvh = h >> 2;
  const int Q0 = qb * 128;
  const int q0w = Q0 + wv * 32;                     // this wave's q-tile base
  const int nsteps = 2 * qb + 2;
  const bf16x8 vones = ones8();
  u16* pw0 = &Ps[wv][0][0];
  u16* pw1 = &Ps[wv][1][0];

  // staging lane decomposition (async16: LDS = uniform base + lane*16B)
  const int keyl = lane >> 4, kch = lane & 15;      // K: 4 rows x 16 chunks
  const int dll = lane >> 3, vch = lane & 7;        // V: 8 rows x 8 chunks
  const u16* Kg = qkvb + (size_t)(b * 2048) * 6144 + 4096 + kvh * 128;
  const u16* Vg = vtb + (size_t)((b * 8 + kvh) * 128) * 2048;

  auto stageK = [&](int j0) {
#pragma unroll
    for (int i = 0; i < 4; i++) {
      const int key = wv * 16 + i * 4 + keyl;
      async16(Kg + (size_t)(j0 + key) * 6144 + ((kch ^ (key & 7)) * 8),
              (u16*)Ks + (wv * 16 + i * 4) * 128 + lane * 8);
    }
  };
  auto stageV = [&](int j0, int vb) {
#pragma unroll
    for (int i = 0; i < 4; i++) {
      const int d = wv * 32 + i * 8 + dll;
      async16(Vg + (size_t)d * 2048 + j0 + ((vch ^ (d & 7)) * 8),
              (u16*)&Vs[vb][0] + (wv * 32 + i * 8) * 64 + lane * 8);
    }
  };

  // Q fragments (global, once per block)
  bf16x8 qf[2][4];
#pragma unroll
  for (int m = 0; m < 2; m++) {
    const u16* qp =
        qkvb + (size_t)(b * 2048 + q0w + m * 16 + c15) * 6144 + h * 128 + g * 8;
#pragma unroll
    for (int c = 0; c < 4; c++) qf[m][c] = ld8(qp + c * 32);
  }

  AttnState st;
#pragma unroll
  for (int m = 0; m < 2; m++) {
#pragma unroll
    for (int dt = 0; dt < 9; dt++) st.acc[m][dt] = f32x4{0.f, 0.f, 0.f, 0.f};
#pragma unroll
    for (int r = 0; r < 4; r++) st.mrun[m][r] = -INFINITY;
  }

  stageK(0);
  stageV(0, 0);

  for (int jt = 0; jt < nsteps; ++jt) {
    const int j0 = jt * 64;
    __syncthreads();   // B1: this step's K/V staged; prior buffer reads done
    // per-wave causal mode: 0=FULL, 1=MASK, 2=SKIP
    const int mode = (j0 + 64 <= q0w) ? 0 : ((j0 <= q0w + 31) ? 1 : 2);
    f32x4 sc[2][4];
    if (mode == 0) qk_phase<true>(j0, q0w, (const u16*)Ks, qf, sc, g, c15);
    else if (mode == 1) qk_phase<false>(j0, q0w, (const u16*)Ks, qf, sc, g, c15);
    __syncthreads();   // B2: all waves' Ks reads complete
    if (jt + 1 < nsteps) {                 // stage next tiles; softmax+PV
      stageK(j0 + 64);                     // hides their latency
      stageV(j0 + 64, (jt + 1) & 1);
    }
    const u16* Vsp = (const u16*)&Vs[jt & 1][0];
    if (mode == 0) smax_pv<true>(j0, q0w, Vsp, pw0, pw1, sc, st, g, c15, vones);
    else if (mode == 1) smax_pv<false>(j0, q0w, Vsp, pw0, pw1, sc, st, g, c15, vones);
  }

  // epilogue: normalize by l (= acc[8]) and store fp32
#pragma unroll
  for (int m = 0; m < 2; m++)
#pragma unroll
    for (int r = 0; r < 4; r++) {
      const int row = q0w + m * 16 + g * 4 + r;
      float inv = 1.0f / st.acc[m][8][r];
      float* op = out + (size_t)(b * 2048 + row) * 4096 + h * 128;
#pragma unroll
      for (int dt = 0; dt < 8; dt++) op[dt * 16 + c15] = st.acc[m][dt][r] * inv;
    }
}

// ---------------- per-row quantization (fp32 attn -> int8 + scale) ----------------
__global__ __launch_bounds__(256) void quant_kernel(const float* __restrict__ attn,
                                                    s8* __restrict__ aq,
                                                    float* __restrict__ ascale) {
  const int t = blockIdx.x, tid = threadIdx.x;
  const float* row = attn + (size_t)t * 4096;
  f32x4 v[4];
  float am = 0.f;
#pragma unroll
  for (int i = 0; i < 4; i++) {
    v[i] = *(const f32x4*)(row + tid * 16 + i * 4);
#pragma unroll
    for (int r = 0; r < 4; r++) am = fmaxf(am, fabsf(v[i][r]));
  }
#pragma unroll
  for (int m = 1; m <= 32; m <<= 1) am = fmaxf(am, __shfl_xor(am, m));
  __shared__ float red[4];
  if ((tid & 63) == 0) red[tid >> 6] = am;
  __syncthreads();
  am = fmaxf(fmaxf(red[0], red[1]), fmaxf(red[2], red[3]));
  float asc = fmaxf(am, 1e-6f) / 127.0f;
  if (tid == 0) ascale[t] = asc;
  int w[4];
#pragma unroll
  for (int i = 0; i < 4; i++) {
    int bytes[4];
#pragma unroll
    for (int r = 0; r < 4; r++) {
      float q = rintf(v[i][r] / asc);
      q = fminf(127.0f, fmaxf(-127.0f, q));
      bytes[r] = ((int)q) & 255;
    }
    w[i] = bytes[0] | (bytes[1] << 8) | (bytes[2] << 16) | (bytes[3] << 24);
  }
  *(int4*)(aq + (size_t)t * 4096 + tid * 16) = int4{w[0], w[1], w[2], w[3]};
}

// ---------------- launch ----------------
extern "C" void kernel_launch(void* const* d_in, const int* in_sizes, int n_in,
                              void* d_out, int out_size, void* d_ws, size_t ws_size,
                              hipStream_t stream) {
  const int* q_hidden = (const int*)d_in[0];
  const float* q_scale = (const float*)d_in[1];
  const int* w_qkv = (const int*)d_in[3];
  const float* s_qkv = (const float*)d_in[4];
  const int* w_o = (const int*)d_in[5];
  const float* s_o = (const float*)d_in[6];
  float* out = (float*)d_out;

  char* ws = (char*)d_ws;
  const size_t MB = 1024 * 1024;
  // ws layout (96 MB peak, regions reused across phases):
  s8* WB = (s8*)(ws);                  // [0,24MB) w_qkv i8 (dead after gemm1)
  u16* QKVB = (u16*)(ws + 48 * MB);    // [48,96MB) qkv bf16 (dead after attention)
  u16* VTB = (u16*)(ws);               // [0,8MB) V^T (after gemm1)
  s8* ATTNQ = (s8*)(ws + 8 * MB);      // [8,~24.8MB) attn_q i8
  float* ASC = (float*)(ws + 25 * MB); // [25MB,+16KB) per-row scales
  s8* WOB = (s8*)(ws + 48 * MB);       // [48,~64.8MB) w_o i8 (after attention)
  s8* XB = (s8*)d_out;                 // x i8 in d_out (dead after gemm1)

  pack_i8<<<16384, 256, 0, stream>>>(q_hidden, XB);
  pack_i8<<<24576, 256, 0, stream>>>(w_qkv, WB);
  gemm_i8<u16><<<dim3(96, 32), 256, 0, stream>>>(XB, WB, s_qkv, q_scale, QKVB,
                                                 T_, OQKV_, HID_);
  rope_kernel<<<10240, 256, 0, stream>>>(QKVB);
  vt_transpose<<<dim3(32, 2, 16), 256, 0, stream>>>(QKVB, VTB);
  attn_kernel<<<dim3(32, 2, 16), 256, 0, stream>>>(QKVB, VTB, out);
  quant_kernel<<<4096, 256, 0, stream>>>(out, ATTNQ, ASC);
  pack_i8<<<16384, 256, 0, stream>>>(w_o, WOB);
  gemm_i8<float><<<dim3(64, 32), 256, 0, stream>>>(ATTNQ, WOB, s_o, ASC, out,
                                                   T_, HID_, HID_);
}